// Round 1
// baseline (359.523 us; speedup 1.0000x reference)
//
#include <hip/hip_runtime.h>
#include <math.h>

#define IMG 512
#define TW 64      // output tile width
#define TH 16      // output tile height
#define RS 84      // LDS row stride (floats): 21 granules/row, odd -> uniform granule banks for b128
#define NCP 39     // float2 col-pairs per row: local cols 0..77 = global x0-8 .. x0+69
#define NV (NCP * 8)   // 312 vertical-pass tasks (39 pairs x 8 row-pairs)
#define MMB 1024   // minmax stage-1 blocks

struct W11 { float w[11]; };

__device__ __forceinline__ unsigned omap(float f) {
  unsigned b = __float_as_uint(f);
  return (b & 0x80000000u) ? ~b : (b | 0x80000000u);
}
__device__ __forceinline__ float ounmap(unsigned u) {
  return __uint_as_float((u & 0x80000000u) ? (u ^ 0x80000000u) : ~u);
}

// Stage 1: per-block partial min/max -> disjoint slots, no atomics.
__global__ __launch_bounds__(256) void minmax_part(const float4* __restrict__ img,
                                                   int n4, unsigned* __restrict__ part) {
  unsigned mx = 0u, mn = 0xFFFFFFFFu;
  int stride = gridDim.x * blockDim.x;
  for (int i = blockIdx.x * blockDim.x + threadIdx.x; i < n4; i += stride) {
    float4 v = img[i];
    unsigned a = omap(v.x), b = omap(v.y), c = omap(v.z), d = omap(v.w);
    mx = max(mx, max(max(a, b), max(c, d)));
    mn = min(mn, min(min(a, b), min(c, d)));
  }
  #pragma unroll
  for (int off = 32; off > 0; off >>= 1) {
    mx = max(mx, __shfl_down(mx, off));
    mn = min(mn, __shfl_down(mn, off));
  }
  __shared__ unsigned smx[4], smn[4];
  int lane = threadIdx.x & 63, wv = threadIdx.x >> 6;
  if (lane == 0) { smx[wv] = mx; smn[wv] = mn; }
  __syncthreads();
  if (threadIdx.x == 0) {
    mx = max(max(smx[0], smx[1]), max(smx[2], smx[3]));
    mn = min(min(smn[0], smn[1]), min(smn[2], smn[3]));
    part[2 * blockIdx.x]     = mx;
    part[2 * blockIdx.x + 1] = mn;
  }
}

// Stage 2: fold MMB partial pairs into ws[0]=max, ws[1]=min.
__global__ __launch_bounds__(256) void minmax_final(const unsigned* __restrict__ part,
                                                    unsigned* __restrict__ ws) {
  unsigned mx = 0u, mn = 0xFFFFFFFFu;
  for (int i = threadIdx.x; i < MMB; i += 256) {
    mx = max(mx, part[2 * i]);
    mn = min(mn, part[2 * i + 1]);
  }
  #pragma unroll
  for (int off = 32; off > 0; off >>= 1) {
    mx = max(mx, __shfl_down(mx, off));
    mn = min(mn, __shfl_down(mn, off));
  }
  __shared__ unsigned smx[4], smn[4];
  int lane = threadIdx.x & 63, wv = threadIdx.x >> 6;
  if (lane == 0) { smx[wv] = mx; smn[wv] = mn; }
  __syncthreads();
  if (threadIdx.x == 0) {
    ws[0] = max(max(smx[0], smx[1]), max(smx[2], smx[3]));
    ws[1] = min(min(smn[0], smn[1]), min(smn[2], smn[3]));
  }
}

// Fused SSIM, v-first: vertical conv in registers (coalesced float2 global loads,
// no LDS), write 5 v-fields to LDS once (b64), horizontal conv reads contiguous
// b128 rows. Previous h-first version was LDS-port bound (480 ds_read_b32/block);
// this cuts LDS wave-instrs ~4.7x and conv FMAs ~18% (intermediate 16x78 < 26x64).
__global__ __launch_bounds__(320, 6) void ssim_k(const float* __restrict__ img1,
                                                 const float* __restrict__ img2,
                                                 float* __restrict__ out,
                                                 const unsigned* __restrict__ ws,
                                                 W11 wv) {
  __shared__ float V[5][TH][RS];   // v-conv of: x1, x2, x1^2, x2^2, x1*x2 (26.9 KB)

  const int tid = threadIdx.x;
  const int bx = blockIdx.x, by = blockIdx.y, n = blockIdx.z;
  const float* p1 = img1 + (size_t)n * IMG * IMG;
  const float* p2 = img2 + (size_t)n * IMG * IMG;
  const int x0 = bx * TW;
  const int y0 = by * TH;

  // C1/C2 (scalar loads issued early; needed after the barrier)
  float L = ounmap(ws[0]) - ounmap(ws[1]);
  if (L == 0.f) L = 5.f;
  float C1 = 0.01f * L; C1 *= C1;
  float C2 = 0.03f * L; C2 *= C2;

  // ---- vertical pass: thread = (2 adjacent cols, 2 output rows) ----
  if (tid < NV) {
    const int q  = tid / NCP;          // row-pair 0..7
    const int p  = tid - q * NCP;      // col-pair 0..38
    const int lx = 2 * p;              // local col 0..76
    const int gx = x0 - 8 + lx;        // global col (x0-8 is 8-float aligned)
    const int gy0 = y0 - 5 + 2 * q;    // global row of input i=0 (12 rows used)

    float acc[5][2][2];                // [field][out row j][col c]
    #pragma unroll
    for (int f = 0; f < 5; ++f) {
      acc[f][0][0] = 0.f; acc[f][0][1] = 0.f;
      acc[f][1][0] = 0.f; acc[f][1][1] = 0.f;
    }

#define VSTEP(i, A0, A1, B0, B1)                                              \
    {                                                                         \
      float f0o = (A0), f0e = (A1), f1o = (B0), f1e = (B1);                   \
      float f2o = f0o * f0o, f2e = f0e * f0e;                                 \
      float f3o = f1o * f1o, f3e = f1e * f1e;                                 \
      float f4o = f0o * f1o, f4e = f0e * f1e;                                 \
      if ((i) < 11) { float wk = wv.w[(i)];                                   \
        acc[0][0][0] += wk * f0o; acc[0][0][1] += wk * f0e;                   \
        acc[1][0][0] += wk * f1o; acc[1][0][1] += wk * f1e;                   \
        acc[2][0][0] += wk * f2o; acc[2][0][1] += wk * f2e;                   \
        acc[3][0][0] += wk * f3o; acc[3][0][1] += wk * f3e;                   \
        acc[4][0][0] += wk * f4o; acc[4][0][1] += wk * f4e; }                 \
      if ((i) > 0) { float wk = wv.w[(i) - 1];                                \
        acc[0][1][0] += wk * f0o; acc[0][1][1] += wk * f0e;                   \
        acc[1][1][0] += wk * f1o; acc[1][1][1] += wk * f1e;                   \
        acc[2][1][0] += wk * f2o; acc[2][1][1] += wk * f2e;                   \
        acc[3][1][0] += wk * f3o; acc[3][1][1] += wk * f3e;                   \
        acc[4][1][0] += wk * f4o; acc[4][1][1] += wk * f4e; }                 \
    }

    const bool inter = (bx > 0) & (bx < IMG / TW - 1) & (by > 0) & (by < IMG / TH - 1);
    if (inter) {
      const float2* A = (const float2*)(p1 + (size_t)gy0 * IMG + gx);
      const float2* B = (const float2*)(p2 + (size_t)gy0 * IMG + gx);
      #pragma unroll
      for (int i = 0; i < 12; ++i) {
        float2 a = A[i * (IMG / 2)];
        float2 b = B[i * (IMG / 2)];
        VSTEP(i, a.x, a.y, b.x, b.y);
      }
    } else {
      const bool c0 = ((unsigned)gx < IMG), c1 = ((unsigned)(gx + 1) < IMG);
      #pragma unroll
      for (int i = 0; i < 12; ++i) {
        int row = gy0 + i;
        float a0 = 0.f, a1 = 0.f, b0 = 0.f, b1 = 0.f;
        if ((unsigned)row < IMG) {
          const float* r1 = p1 + (size_t)row * IMG;
          const float* r2 = p2 + (size_t)row * IMG;
          if (c0) { a0 = r1[gx];     b0 = r2[gx];     }
          if (c1) { a1 = r1[gx + 1]; b1 = r2[gx + 1]; }
        }
        VSTEP(i, a0, a1, b0, b1);
      }
    }
#undef VSTEP

    const int r0 = 2 * q;
    #pragma unroll
    for (int f = 0; f < 5; ++f) {
      *(float2*)&V[f][r0][lx]     = make_float2(acc[f][0][0], acc[f][0][1]);
      *(float2*)&V[f][r0 + 1][lx] = make_float2(acc[f][1][0], acc[f][1][1]);
    }
  }
  __syncthreads();   // the only barrier

  // ---- horizontal pass: 128 threads = (8 cols, 1 row); contiguous b128 reads.
  // lane->(r=tid&15) makes consecutive 8 lanes hit 8 distinct granule banks (RS=84 odd*4).
  if (tid < 128) {
    const int r  = tid & 15;
    const int c8 = (tid >> 4) << 3;    // 0,8,...,56

    float acc[5][8];
    #pragma unroll
    for (int f = 0; f < 5; ++f)
      #pragma unroll
      for (int c = 0; c < 8; ++c) acc[f][c] = 0.f;

    #pragma unroll
    for (int f = 0; f < 5; ++f) {
      float v[24];
      #pragma unroll
      for (int m = 0; m < 6; ++m)
        *(float4*)&v[4 * m] = *(const float4*)&V[f][r][c8 + 4 * m];
      // output col c taps local cols (c8+c+3)..(c8+c+13) -> v[c+3+k]
      #pragma unroll
      for (int k = 0; k < 11; ++k) {
        float wk = wv.w[k];
        #pragma unroll
        for (int c = 0; c < 8; ++c) acc[f][c] += wk * v[c + 3 + k];
      }
    }

    float res[8];
    #pragma unroll
    for (int c = 0; c < 8; ++c) {
      float mu1 = acc[0][c], mu2 = acc[1][c];
      float mu1s = mu1 * mu1, mu2s = mu2 * mu2, mu12 = mu1 * mu2;
      float s1 = acc[2][c] - mu1s, s2 = acc[3][c] - mu2s, s12 = acc[4][c] - mu12;
      float num = (2.f * mu12 + C1) * (2.f * s12 + C2);
      float den = (mu1s + mu2s + C1) * (s1 + s2 + C2);
      res[c] = num / den;
    }
    float* op = out + (size_t)n * IMG * IMG + (size_t)(y0 + r) * IMG + x0 + c8;
    *(float4*)&op[0] = make_float4(res[0], res[1], res[2], res[3]);
    *(float4*)&op[4] = make_float4(res[4], res[5], res[6], res[7]);
  }
}

extern "C" void kernel_launch(void* const* d_in, const int* in_sizes, int n_in,
                              void* d_out, int out_size, void* d_ws, size_t ws_size,
                              hipStream_t stream) {
  const float* img1 = (const float*)d_in[0];
  const float* img2 = (const float*)d_in[1];
  float* out = (float*)d_out;
  unsigned* ws = (unsigned*)d_ws;          // [0..1]: final max/min; [16..]: partials
  unsigned* part = ws + 16;
  int n = in_sizes[0];             // 32*1*512*512
  int batch = n / (IMG * IMG);     // 32

  // Gaussian window, center at ws/2 = 5.5 (asymmetric!), normalized
  W11 wv;
  double g[11], s = 0.0;
  for (int i = 0; i < 11; ++i) { double d = i - 5.5; g[i] = exp(-(d * d) / 4.5); s += g[i]; }
  for (int i = 0; i < 11; ++i) wv.w[i] = (float)(g[i] / s);

  minmax_part<<<MMB, 256, 0, stream>>>((const float4*)img1, n / 4, part);
  minmax_final<<<1, 256, 0, stream>>>(part, ws);
  dim3 grid(IMG / TW, IMG / TH, batch);
  ssim_k<<<grid, 320, 0, stream>>>(img1, img2, out, ws, wv);
}

// Round 2
// 184.886 us; speedup vs baseline: 1.9446x; 1.9446x over previous
//
#include <hip/hip_runtime.h>
#include <math.h>

#define IMG 512
#define TW 64      // output tile width
#define TH 16      // output tile height
#define RS 84      // LDS row stride (floats): 336B = 21 granules/row, odd -> uniform bank spread, 16B-aligned rows
#define NCP 39     // float2 col-pairs per row: local cols 0..77 = global x0-8 .. x0+69
#define NV (NCP * 8)   // 312 vertical-pass tasks (39 pairs x 8 row-pairs)
#define MMB 1024   // minmax stage-1 blocks

struct W11 { float w[11]; };

__device__ __forceinline__ unsigned omap(float f) {
  unsigned b = __float_as_uint(f);
  return (b & 0x80000000u) ? ~b : (b | 0x80000000u);
}
__device__ __forceinline__ float ounmap(unsigned u) {
  return __uint_as_float((u & 0x80000000u) ? (u ^ 0x80000000u) : ~u);
}

// Stage 1: per-block partial min/max -> disjoint slots, no atomics.
__global__ __launch_bounds__(256) void minmax_part(const float4* __restrict__ img,
                                                   int n4, unsigned* __restrict__ part) {
  unsigned mx = 0u, mn = 0xFFFFFFFFu;
  int stride = gridDim.x * blockDim.x;
  for (int i = blockIdx.x * blockDim.x + threadIdx.x; i < n4; i += stride) {
    float4 v = img[i];
    unsigned a = omap(v.x), b = omap(v.y), c = omap(v.z), d = omap(v.w);
    mx = max(mx, max(max(a, b), max(c, d)));
    mn = min(mn, min(min(a, b), min(c, d)));
  }
  #pragma unroll
  for (int off = 32; off > 0; off >>= 1) {
    mx = max(mx, __shfl_down(mx, off));
    mn = min(mn, __shfl_down(mn, off));
  }
  __shared__ unsigned smx[4], smn[4];
  int lane = threadIdx.x & 63, wv = threadIdx.x >> 6;
  if (lane == 0) { smx[wv] = mx; smn[wv] = mn; }
  __syncthreads();
  if (threadIdx.x == 0) {
    mx = max(max(smx[0], smx[1]), max(smx[2], smx[3]));
    mn = min(min(smn[0], smn[1]), min(smn[2], smn[3]));
    part[2 * blockIdx.x]     = mx;
    part[2 * blockIdx.x + 1] = mn;
  }
}

// Stage 2: fold MMB partial pairs into ws[0]=max, ws[1]=min.
__global__ __launch_bounds__(256) void minmax_final(const unsigned* __restrict__ part,
                                                    unsigned* __restrict__ ws) {
  unsigned mx = 0u, mn = 0xFFFFFFFFu;
  for (int i = threadIdx.x; i < MMB; i += 256) {
    mx = max(mx, part[2 * i]);
    mn = min(mn, part[2 * i + 1]);
  }
  #pragma unroll
  for (int off = 32; off > 0; off >>= 1) {
    mx = max(mx, __shfl_down(mx, off));
    mn = min(mn, __shfl_down(mn, off));
  }
  __shared__ unsigned smx[4], smn[4];
  int lane = threadIdx.x & 63, wv = threadIdx.x >> 6;
  if (lane == 0) { smx[wv] = mx; smn[wv] = mn; }
  __syncthreads();
  if (threadIdx.x == 0) {
    ws[0] = max(max(smx[0], smx[1]), max(smx[2], smx[3]));
    ws[1] = min(min(smn[0], smn[1]), min(smn[2], smn[3]));
  }
}

// Fused SSIM, v-first, 4 fields: vertical conv in registers (coalesced float2
// global loads, no LDS), write v-conv of {a, b, a^2+b^2, a*b} to LDS (conv is
// linear so sigma1_sq+sigma2_sq needs only the SUM field), horizontal conv
// reads contiguous b128 rows.
// Round-1 lesson: h-pass scratch spill (float v[24] declared inside the
// unrolled field loop + float4 pointer-punning defeated SROA -> 548MB of
// stack traffic). Fix: named float4 temporaries, component-wise copies into a
// function-scope array, constant indices only.
__global__ __launch_bounds__(320, 4) void ssim_k(const float* __restrict__ img1,
                                                 const float* __restrict__ img2,
                                                 float* __restrict__ out,
                                                 const unsigned* __restrict__ ws,
                                                 W11 wv) {
  __shared__ float V[4][TH][RS];   // 21504 B

  const int tid = threadIdx.x;
  const int bx = blockIdx.x, by = blockIdx.y, n = blockIdx.z;
  const float* p1 = img1 + (size_t)n * IMG * IMG;
  const float* p2 = img2 + (size_t)n * IMG * IMG;
  const int x0 = bx * TW;
  const int y0 = by * TH;

  // C1/C2 (scalar loads issued early; needed after the barrier)
  float L = ounmap(ws[0]) - ounmap(ws[1]);
  if (L == 0.f) L = 5.f;
  float C1 = 0.01f * L; C1 *= C1;
  float C2 = 0.03f * L; C2 *= C2;

  // ---- vertical pass: thread = (2 adjacent cols, 2 output rows) ----
  if (tid < NV) {
    const int q  = tid / NCP;          // row-pair 0..7
    const int p  = tid - q * NCP;      // col-pair 0..38
    const int lx = 2 * p;              // local col 0..76
    const int gx = x0 - 8 + lx;        // global col (x0-8 is 8-float aligned)
    const int gy0 = y0 - 5 + 2 * q;    // global row of input i=0 (12 rows used)

    float acc[4][2][2];                // [field][out row j][col c]
    #pragma unroll
    for (int f = 0; f < 4; ++f) {
      acc[f][0][0] = 0.f; acc[f][0][1] = 0.f;
      acc[f][1][0] = 0.f; acc[f][1][1] = 0.f;
    }

#define VSTEP(i, A0, A1, B0, B1)                                              \
    {                                                                         \
      float f0o = (A0), f0e = (A1), f1o = (B0), f1e = (B1);                   \
      float f2o = f0o * f0o + f1o * f1o;  /* a^2+b^2 */                       \
      float f2e = f0e * f0e + f1e * f1e;                                      \
      float f3o = f0o * f1o, f3e = f0e * f1e;   /* a*b */                     \
      if ((i) < 11) { float wk = wv.w[(i)];                                   \
        acc[0][0][0] += wk * f0o; acc[0][0][1] += wk * f0e;                   \
        acc[1][0][0] += wk * f1o; acc[1][0][1] += wk * f1e;                   \
        acc[2][0][0] += wk * f2o; acc[2][0][1] += wk * f2e;                   \
        acc[3][0][0] += wk * f3o; acc[3][0][1] += wk * f3e; }                 \
      if ((i) > 0) { float wk = wv.w[(i) - 1];                                \
        acc[0][1][0] += wk * f0o; acc[0][1][1] += wk * f0e;                   \
        acc[1][1][0] += wk * f1o; acc[1][1][1] += wk * f1e;                   \
        acc[2][1][0] += wk * f2o; acc[2][1][1] += wk * f2e;                   \
        acc[3][1][0] += wk * f3o; acc[3][1][1] += wk * f3e; }                 \
    }

    const bool inter = (bx > 0) & (bx < IMG / TW - 1) & (by > 0) & (by < IMG / TH - 1);
    if (inter) {
      const float2* A = (const float2*)(p1 + (size_t)gy0 * IMG + gx);
      const float2* B = (const float2*)(p2 + (size_t)gy0 * IMG + gx);
      #pragma unroll
      for (int i = 0; i < 12; ++i) {
        float2 a = A[i * (IMG / 2)];
        float2 b = B[i * (IMG / 2)];
        VSTEP(i, a.x, a.y, b.x, b.y);
      }
    } else {
      const bool c0 = ((unsigned)gx < IMG), c1 = ((unsigned)(gx + 1) < IMG);
      #pragma unroll
      for (int i = 0; i < 12; ++i) {
        int row = gy0 + i;
        float a0 = 0.f, a1 = 0.f, b0 = 0.f, b1 = 0.f;
        if ((unsigned)row < IMG) {
          const float* r1 = p1 + (size_t)row * IMG;
          const float* r2 = p2 + (size_t)row * IMG;
          if (c0) { a0 = r1[gx];     b0 = r2[gx];     }
          if (c1) { a1 = r1[gx + 1]; b1 = r2[gx + 1]; }
        }
        VSTEP(i, a0, a1, b0, b1);
      }
    }
#undef VSTEP

    const int r0 = 2 * q;
    #pragma unroll
    for (int f = 0; f < 4; ++f) {
      *(float2*)&V[f][r0][lx]     = make_float2(acc[f][0][0], acc[f][0][1]);
      *(float2*)&V[f][r0 + 1][lx] = make_float2(acc[f][1][0], acc[f][1][1]);
    }
  }
  __syncthreads();   // the only barrier

  // ---- horizontal pass: 128 threads = (8 cols, 1 row); contiguous b128 reads.
  // Bank check: lane (r,c8) start bank-group = (5r + c8/4) mod 8; over 64 lanes
  // each group gets exactly 8 lanes -> conflict-free at the b128 minimum rate.
  if (tid < 128) {
    const int r  = tid & 15;
    const int c8 = (tid >> 4) << 3;    // 0,8,...,56

    float acc[4][8];
    #pragma unroll
    for (int f = 0; f < 4; ++f)
      #pragma unroll
      for (int c = 0; c < 8; ++c) acc[f][c] = 0.f;

    float v[24];   // function scope, constant-index scalar writes only (no punning)
    #pragma unroll
    for (int f = 0; f < 4; ++f) {
      const float* row = &V[f][r][c8];
      float4 t0 = *(const float4*)(row + 0);
      float4 t1 = *(const float4*)(row + 4);
      float4 t2 = *(const float4*)(row + 8);
      float4 t3 = *(const float4*)(row + 12);
      float4 t4 = *(const float4*)(row + 16);
      float4 t5 = *(const float4*)(row + 20);
      v[0]  = t0.x; v[1]  = t0.y; v[2]  = t0.z; v[3]  = t0.w;
      v[4]  = t1.x; v[5]  = t1.y; v[6]  = t1.z; v[7]  = t1.w;
      v[8]  = t2.x; v[9]  = t2.y; v[10] = t2.z; v[11] = t2.w;
      v[12] = t3.x; v[13] = t3.y; v[14] = t3.z; v[15] = t3.w;
      v[16] = t4.x; v[17] = t4.y; v[18] = t4.z; v[19] = t4.w;
      v[20] = t5.x; v[21] = t5.y; v[22] = t5.z; v[23] = t5.w;
      // output col c taps local cols (c8+c+3)..(c8+c+13) -> v[c+3+k], j in [3,20]
      #pragma unroll
      for (int k = 0; k < 11; ++k) {
        float wk = wv.w[k];
        #pragma unroll
        for (int c = 0; c < 8; ++c) acc[f][c] += wk * v[c + 3 + k];
      }
    }

    float res[8];
    #pragma unroll
    for (int c = 0; c < 8; ++c) {
      float mu1 = acc[0][c], mu2 = acc[1][c];
      float mu1s = mu1 * mu1, mu2s = mu2 * mu2, mu12 = mu1 * mu2;
      float sS  = acc[2][c] - mu1s - mu2s;   // sigma1_sq + sigma2_sq
      float s12 = acc[3][c] - mu12;
      float num = (2.f * mu12 + C1) * (2.f * s12 + C2);
      float den = (mu1s + mu2s + C1) * (sS + C2);
      res[c] = num / den;
    }
    float* op = out + (size_t)n * IMG * IMG + (size_t)(y0 + r) * IMG + x0 + c8;
    *(float4*)&op[0] = make_float4(res[0], res[1], res[2], res[3]);
    *(float4*)&op[4] = make_float4(res[4], res[5], res[6], res[7]);
  }
}

extern "C" void kernel_launch(void* const* d_in, const int* in_sizes, int n_in,
                              void* d_out, int out_size, void* d_ws, size_t ws_size,
                              hipStream_t stream) {
  const float* img1 = (const float*)d_in[0];
  const float* img2 = (const float*)d_in[1];
  float* out = (float*)d_out;
  unsigned* ws = (unsigned*)d_ws;          // [0..1]: final max/min; [16..]: partials
  unsigned* part = ws + 16;
  int n = in_sizes[0];             // 32*1*512*512
  int batch = n / (IMG * IMG);     // 32

  // Gaussian window, center at ws/2 = 5.5 (asymmetric!), normalized
  W11 wv;
  double g[11], s = 0.0;
  for (int i = 0; i < 11; ++i) { double d = i - 5.5; g[i] = exp(-(d * d) / 4.5); s += g[i]; }
  for (int i = 0; i < 11; ++i) wv.w[i] = (float)(g[i] / s);

  minmax_part<<<MMB, 256, 0, stream>>>((const float4*)img1, n / 4, part);
  minmax_final<<<1, 256, 0, stream>>>(part, ws);
  dim3 grid(IMG / TW, IMG / TH, batch);
  ssim_k<<<grid, 320, 0, stream>>>(img1, img2, out, ws, wv);
}